// Round 4
// baseline (482.892 us; speedup 1.0000x reference)
//
#include <hip/hip_runtime.h>
#include <hip/hip_bf16.h>

typedef unsigned short ushort_t;
typedef __bf16 bf16_t;
typedef bf16_t bf16x8 __attribute__((ext_vector_type(8)));
typedef float floatx4 __attribute__((ext_vector_type(4)));
typedef ushort_t ushortx8 __attribute__((ext_vector_type(8)));

struct alignas(8) us4 { ushort_t x, y, z, w; };

__device__ __forceinline__ ushort_t f2bf(float f) {
  union { float f; unsigned int u; } v; v.f = f;
  unsigned int u = v.u;
  return (ushort_t)((u + 0x7fffu + ((u >> 16) & 1u)) >> 16);
}

__device__ __forceinline__ unsigned int pk_bf16(float a, float b) {
  __hip_bfloat162 h = __float22bfloat162_rn(float2{a, b});  // .x in low half
  union { __hip_bfloat162 h; unsigned int u; } v; v.h = h;
  return v.u;
}

__device__ __forceinline__ void async16(const void* g, void* l) {
  __builtin_amdgcn_global_load_lds(
      (const __attribute__((address_space(1))) unsigned int*)g,
      (__attribute__((address_space(3))) unsigned int*)l, 16, 0, 0);
}

#define LOG2E 1.44269504088896340736f

// ---------------- fused prep: cvt x -> bf16, transpose-cast W_qkv, W_proj ----

__global__ __launch_bounds__(256) void k_prep(const float* __restrict__ x,
                                              ushort_t* __restrict__ xb,
                                              const float* __restrict__ Wq,
                                              ushort_t* __restrict__ WqT,
                                              const float* __restrict__ Wp,
                                              ushort_t* __restrict__ WpT) {
  __shared__ float tile[32][33];
  const int bid = blockIdx.x, t = threadIdx.x;
  if (bid < 6144) {
    size_t i = ((size_t)bid * 256 + t) * 8;
    float4 a = *(const float4*)(x + i);
    float4 b = *(const float4*)(x + i + 4);
    ushortx8 o;
    o[0] = f2bf(a.x); o[1] = f2bf(a.y); o[2] = f2bf(a.z); o[3] = f2bf(a.w);
    o[4] = f2bf(b.x); o[5] = f2bf(b.y); o[6] = f2bf(b.z); o[7] = f2bf(b.w);
    *(ushortx8*)(xb + i) = o;
    return;
  }
  const float* in; ushort_t* out; int C, c0, r0;
  if (bid < 7872) {
    int b2 = bid - 6144;
    in = Wq; out = WqT; C = 2304;
    c0 = (b2 % 72) * 32; r0 = (b2 / 72) * 32;
  } else {
    int b3 = bid - 7872;
    in = Wp; out = WpT; C = 768;
    c0 = (b3 % 24) * 32; r0 = (b3 / 24) * 32;
  }
  const int tx = t & 31, ty = t >> 5;  // 32 x 8
#pragma unroll
  for (int i = 0; i < 32; i += 8)
    tile[ty + i][tx] = in[(size_t)(r0 + ty + i) * C + c0 + tx];
  __syncthreads();
#pragma unroll
  for (int i = 0; i < 32; i += 8)
    out[(size_t)(c0 + ty + i) * 768 + r0 + tx] = f2bf(tile[tx][ty + i]);
}

// ------ gemm_bt 2-stage pipelined mainloop (256x128 tile, K=768, BK=32) -----
// Both pipes ~26% busy at occupancy 2 -> stall-bound. Occupancy 3 blocks/CU
// (VGPR 128 <= 170, LDS 48KB*3 <= 160KB) so a third block's compute overlaps
// the others' end-of-iter vmcnt(0) drains.
//
// SWAP=false: acc[i][j][r] -> m = m0+wr*128+i*16+qd*4+r, n = n0+wc*64+j*16+lr
// SWAP=true:  acc[i][j][r] -> m = m0+wr*128+i*16+lr,     n = n0+wc*64+j*16+qd*4+r

template <bool SWAP>
__device__ __forceinline__ void gemm_pipe2(const ushort_t* __restrict__ A,
                                           const ushort_t* __restrict__ Bt,
                                           int m0, int n0,
                                           ushort_t* sA, ushort_t* sB,
                                           floatx4 acc[8][4]) {
  const int t = threadIdx.x;
  const int lane = t & 63;
  const int lr = lane & 15, qd = lane >> 4;
  const int w = t >> 6;
  const int wr = w >> 1, wc = w & 1;
  const int swz = ((t & 3) ^ ((t >> 3) & 3)) * 8;
  const ushort_t* gA = A + (size_t)(m0 + (t >> 2)) * 768 + swz;
  const ushort_t* gB = Bt + (size_t)(n0 + (t >> 2)) * 768 + swz;
  char* lA = (char*)sA + t * 16;
  char* lB = (char*)sB + t * 16;
  const int rsz = (qd ^ ((lr >> 1) & 3)) * 16;
#define ISSUE(kk, buf)                                    \
  do {                                                    \
    const int k0_ = (kk) * 32;                            \
    const int ba_ = (buf) * 16384, bb_ = (buf) * 8192;    \
    async16(gA + k0_, lA + ba_);                          \
    async16(gA + k0_ + 64 * 768, lA + ba_ + 4096);        \
    async16(gA + k0_ + 128 * 768, lA + ba_ + 8192);       \
    async16(gA + k0_ + 192 * 768, lA + ba_ + 12288);      \
    async16(gB + k0_, lB + bb_);                          \
    async16(gB + k0_ + 64 * 768, lB + bb_ + 4096);        \
  } while (0)
  ISSUE(0, 0);
  asm volatile("s_waitcnt vmcnt(0)" ::: "memory");
  asm volatile("s_barrier" ::: "memory");
#pragma unroll
  for (int k = 0; k < 24; ++k) {
    if (k + 1 < 24) ISSUE(k + 1, (k + 1) & 1);
    const char* cA = (const char*)sA + (k & 1) * 16384;
    const char* cB = (const char*)sB + (k & 1) * 8192;
    bf16x8 af[8], bfr[4];
#pragma unroll
    for (int i = 0; i < 8; ++i)
      af[i] = *(const bf16x8*)(cA + (wr * 128 + i * 16 + lr) * 64 + rsz);
#pragma unroll
    for (int j = 0; j < 4; ++j)
      bfr[j] = *(const bf16x8*)(cB + (wc * 64 + j * 16 + lr) * 64 + rsz);
#pragma unroll
    for (int i = 0; i < 8; ++i)
#pragma unroll
      for (int j = 0; j < 4; ++j) {
        if constexpr (SWAP)
          acc[i][j] = __builtin_amdgcn_mfma_f32_16x16x32_bf16(bfr[j], af[i], acc[i][j], 0, 0, 0);
        else
          acc[i][j] = __builtin_amdgcn_mfma_f32_16x16x32_bf16(af[i], bfr[j], acc[i][j], 0, 0, 0);
      }
    if (k + 1 < 24)
      asm volatile("s_waitcnt vmcnt(0)" ::: "memory");  // k+1's 6 loads landed
    if (k < 23) asm volatile("s_barrier" ::: "memory");
  }
#undef ISSUE
}

// ---------------- QKV GEMM + bias + zeta + scale, scatter to q/k/vt ----------------

__global__ __launch_bounds__(256, 3) void k_qkv(const ushort_t* __restrict__ xb,
                                                const ushort_t* __restrict__ WqT,
                                                const float* __restrict__ bqkv,
                                                const float* __restrict__ zeta,
                                                ushort_t* __restrict__ qb,
                                                ushort_t* __restrict__ kb,
                                                ushort_t* __restrict__ vtb) {
  __shared__ alignas(16) ushort_t sA[2 * 8192];
  __shared__ alignas(16) ushort_t sB[2 * 4096];
  floatx4 acc[8][4] = {};
  const int lin = blockIdx.x;
  const int xcd = lin & 7, idx = lin >> 3;           // idx in 0..143
  const int m0 = (xcd * 8 + (idx & 7)) * 256;        // 64 m-panels
  const int n0 = (idx >> 3) * 128;                   // 18 n-tiles
  const int tq = n0 / 768;  // 0=q 1=k 2=v (tile never straddles: 768 % 128 == 0)
  const int t = threadIdx.x, lane = t & 63, w = t >> 6;
  const int wr = w >> 1, wc = w & 1, lr = lane & 15, qd = lane >> 4;
  if (tq < 2) {
    gemm_pipe2<true>(xb, WqT, m0, n0, sA, sB, acc);
    ushort_t* dst = (tq == 0) ? qb : kb;
    const float sc = (tq == 0) ? 0.125f * LOG2E : 1.0f;
#pragma unroll
    for (int j = 0; j < 4; ++j) {
      int n = n0 + wc * 64 + j * 16 + qd * 4;   // + r along d
      int nc = n - tq * 768;
      int h = nc >> 6, dim = n & 63;
      float4 b4 = *(const float4*)&bqkv[n];
      float4 z4 = *(const float4*)&zeta[nc];
      float g0 = z4.x * sc, g1 = z4.y * sc, g2 = z4.z * sc, g3 = z4.w * sc;
#pragma unroll
      for (int i = 0; i < 8; ++i) {
        int m = m0 + wr * 128 + i * 16 + lr;
        int b = m >> 10, seq = m & 1023;
        us4 pk;
        pk.x = f2bf((acc[i][j][0] + b4.x) * g0);
        pk.y = f2bf((acc[i][j][1] + b4.y) * g1);
        pk.z = f2bf((acc[i][j][2] + b4.z) * g2);
        pk.w = f2bf((acc[i][j][3] + b4.w) * g3);
        *(us4*)&dst[(((size_t)b * 12 + h) * 1024 + seq) * 64 + dim] = pk;
      }
    }
  } else {
    gemm_pipe2<false>(xb, WqT, m0, n0, sA, sB, acc);
#pragma unroll
    for (int j = 0; j < 4; ++j) {
      int n = n0 + wc * 64 + j * 16 + lr;
      int nc = n - 2 * 768;
      int h = nc >> 6, dim = n & 63;
      float bias = bqkv[n];
      float zv = zeta[nc];
#pragma unroll
      for (int i = 0; i < 8; ++i) {
        int mbase = m0 + wr * 128 + i * 16 + qd * 4;
        int b = mbase >> 10, seq = mbase & 1023;
        us4 pk;
        pk.x = f2bf((acc[i][j][0] + bias) * zv);
        pk.y = f2bf((acc[i][j][1] + bias) * zv);
        pk.z = f2bf((acc[i][j][2] + bias) * zv);
        pk.w = f2bf((acc[i][j][3] + bias) * zv);
        *(us4*)&vtb[(((size_t)b * 12 + h) * 64 + dim) * 1024 + seq] = pk;
      }
    }
  }
}

// ---------------- flash attention v5: 64-key tiles, double-buffered K/V -----
// Per kt: issue kt+1's 4 DMA ops (K 8KB + V 8KB), compute kt (16 QK mfma +
// softmax + 16 PV mfma), then vmcnt(0)+barrier. DMA latency hides under the
// current tile's compute instead of serializing. Mask hoisted to a one-time
// LDS float table. T5 setprio around MFMA clusters. LDS: 2x16KB stages +
// 16KB P + 4KB mask = 52KB; 3 blocks/CU. unroll 2 keeps st=kt&1 static
// while capping code size (full 16x unroll risked compile blowup).

__global__ __launch_bounds__(256, 3) void k_attn(const ushort_t* __restrict__ qg,
                                                 const ushort_t* __restrict__ kg,
                                                 const ushort_t* __restrict__ vg,
                                                 const unsigned char* __restrict__ mask,
                                                 ushort_t* __restrict__ ob) {
  __shared__ alignas(16) char smem[53248];
  // [0,16384): stage0 (K 8KB, V 8KB)  [16384,32768): stage1
  // [32768,49152): P (4KB/wave)       [49152,53248): maskadd[1024] f32
  float* maskadd = (float*)(smem + 49152);
  const int t = threadIdx.x, lane = t & 63, w = t >> 6;
  const int lr = lane & 15, qd = lane >> 4;
  const int lin = blockIdx.x;
  const int bh = (lin & 7) + 8 * (lin >> 6);
  const int qt = (lin >> 3) & 7;
  const int b = bh / 12, h = bh % 12;
  const int qrow0 = qt * 128 + w * 32;
  const ushort_t* qp = qg + (size_t)bh * 65536;
  const ushort_t* kp = kg + (size_t)bh * 65536;
  const ushort_t* vp = vg + (size_t)bh * 65536;
  const unsigned char* mp = mask + b * 1024;

  bf16x8 qf[2][2];
#pragma unroll
  for (int ns = 0; ns < 2; ++ns)
#pragma unroll
    for (int kk = 0; kk < 2; ++kk)
      qf[ns][kk] = *(const bf16x8*)(qp + (size_t)(qrow0 + ns * 16 + lr) * 64 + kk * 32 + qd * 8);

  floatx4 o[4][2] = {};
  float lst[2] = {0.f, 0.f};
  char* sPw = smem + 32768 + w * 4096;

  {  // mask -> LDS float table, once
    uchar4 mv = *(const uchar4*)(mp + t * 4);
    float4 f;
    f.x = mv.x ? -1e30f : 0.0f;
    f.y = mv.y ? -1e30f : 0.0f;
    f.z = mv.z ? -1e30f : 0.0f;
    f.w = mv.w ? -1e30f : 0.0f;
    *(float4*)&maskadd[t * 4] = f;
  }

  // stage kt: K tile 64 keys x 64 d (128B rows, XOR-swizzled chunks) +
  //           V tile 64 d x 64 seq  (128B rows, XOR-swizzled chunks)
#define STAGE(kt_, st_)                                                   \
  do {                                                                    \
    const ushort_t* kpt_ = kp + (kt_) * 4096;                             \
    const ushort_t* vpt_ = vp + (kt_) * 64;                               \
    _Pragma("unroll")                                                     \
    for (int it = 0; it < 2; ++it) {                                      \
      int p = it * 256 + t;                                               \
      int r = p >> 3, cs = (p & 7) ^ (r & 7);                             \
      async16(kpt_ + r * 64 + cs * 8, smem + (st_) * 16384 + p * 16);     \
      async16(vpt_ + (size_t)r * 1024 + cs * 8,                           \
              smem + (st_) * 16384 + 8192 + p * 16);                      \
    }                                                                     \
  } while (0)

  STAGE(0, 0);
  __syncthreads();  // drains prologue DMA + mask writes

#pragma unroll 2
  for (int kt = 0; kt < 16; ++kt) {
    const int st = kt & 1;
    if (kt + 1 < 16) STAGE(kt + 1, st ^ 1);
    const char* sK = smem + st * 16384;
    const char* sV = smem + st * 16384 + 8192;

    floatx4 s[4][2] = {};
    __builtin_amdgcn_s_setprio(1);
#pragma unroll
    for (int kk = 0; kk < 2; ++kk) {
#pragma unroll
      for (int ms = 0; ms < 4; ++ms) {
        bf16x8 ak = *(const bf16x8*)(sK + (ms * 16 + lr) * 128 +
                                     ((kk * 4 + qd) ^ (lr & 7)) * 16);
#pragma unroll
        for (int ns = 0; ns < 2; ++ns)
          s[ms][ns] = __builtin_amdgcn_mfma_f32_16x16x32_bf16(ak, qf[ns][kk], s[ms][ns], 0, 0, 0);
      }
    }
    __builtin_amdgcn_s_setprio(0);

#pragma unroll
    for (int ms = 0; ms < 4; ++ms) {
      float4 mk = *(const float4*)&maskadd[kt * 64 + ms * 16 + qd * 4];
#pragma unroll
      for (int ns = 0; ns < 2; ++ns) {
        float p0 = __builtin_amdgcn_exp2f(s[ms][ns][0] + mk.x);
        float p1 = __builtin_amdgcn_exp2f(s[ms][ns][1] + mk.y);
        float p2 = __builtin_amdgcn_exp2f(s[ms][ns][2] + mk.z);
        float p3 = __builtin_amdgcn_exp2f(s[ms][ns][3] + mk.w);
        lst[ns] += (p0 + p1) + (p2 + p3);
        uint2 pk;
        pk.x = pk_bf16(p0, p1);
        pk.y = pk_bf16(p2, p3);
        *(uint2*)(sPw + (ns * 16 + lr) * 128 +
                  ((ms * 2 + (qd >> 1)) ^ (lr & 7)) * 16 + (qd & 1) * 8) = pk;
      }
    }
    asm volatile("s_waitcnt lgkmcnt(0)" ::: "memory");
    __builtin_amdgcn_sched_barrier(0);

    __builtin_amdgcn_s_setprio(1);
#pragma unroll
    for (int kk = 0; kk < 2; ++kk) {
      bf16x8 pb[2];
#pragma unroll
      for (int ns = 0; ns < 2; ++ns)
        pb[ns] = *(const bf16x8*)(sPw + (ns * 16 + lr) * 128 +
                                  ((kk * 4 + qd) ^ (lr & 7)) * 16);
#pragma unroll
      for (int ds = 0; ds < 4; ++ds) {
        bf16x8 av = *(const bf16x8*)(sV + (ds * 16 + lr) * 128 +
                                     ((kk * 4 + qd) ^ (lr & 7)) * 16);
#pragma unroll
        for (int ns = 0; ns < 2; ++ns)
          o[ds][ns] = __builtin_amdgcn_mfma_f32_16x16x32_bf16(av, pb[ns], o[ds][ns], 0, 0, 0);
      }
    }
    __builtin_amdgcn_s_setprio(0);

    if (kt + 1 < 16) {
      asm volatile("s_waitcnt vmcnt(0)" ::: "memory");  // kt+1's stage landed
      asm volatile("s_barrier" ::: "memory");
    }
  }
#undef STAGE

#pragma unroll
  for (int ns = 0; ns < 2; ++ns) {
    lst[ns] += __shfl_xor(lst[ns], 16);
    lst[ns] += __shfl_xor(lst[ns], 32);
  }
#pragma unroll
  for (int ns = 0; ns < 2; ++ns) {
    float rl = 1.0f / lst[ns];
    size_t row = (size_t)(b * 1024 + qrow0 + ns * 16 + lr) * 768 + h * 64;
#pragma unroll
    for (int ds = 0; ds < 4; ++ds) {
      uint2 ov;
      ov.x = pk_bf16(o[ds][ns][0] * rl, o[ds][ns][1] * rl);
      ov.y = pk_bf16(o[ds][ns][2] * rl, o[ds][ns][3] * rl);
      *(uint2*)&ob[row + ds * 16 + qd * 4] = ov;
    }
  }
}

// ---------------- output projection (SWAP=true -> float4 stores) ------------

__global__ __launch_bounds__(256, 3) void k_proj(const ushort_t* __restrict__ ob,
                                                 const ushort_t* __restrict__ WpT,
                                                 const float* __restrict__ bproj,
                                                 float* __restrict__ out) {
  __shared__ alignas(16) ushort_t sA[2 * 8192];
  __shared__ alignas(16) ushort_t sB[2 * 4096];
  floatx4 acc[8][4] = {};
  const int lin = blockIdx.x;
  const int xcd = lin & 7, idx = lin >> 3;           // idx in 0..47
  const int m0 = (xcd * 8 + (idx & 7)) * 256;
  const int n0 = (idx >> 3) * 128;                   // 6 n-tiles
  gemm_pipe2<true>(ob, WpT, m0, n0, sA, sB, acc);
  const int t = threadIdx.x, lane = t & 63, w = t >> 6;
  const int wr = w >> 1, wc = w & 1, lr = lane & 15, qd = lane >> 4;
#pragma unroll
  for (int j = 0; j < 4; ++j) {
    int n = n0 + wc * 64 + j * 16 + qd * 4;
    float4 b4 = *(const float4*)&bproj[n];
#pragma unroll
    for (int i = 0; i < 8; ++i) {
      int m = m0 + wr * 128 + i * 16 + lr;
      float4 o;
      o.x = acc[i][j][0] + b4.x;
      o.y = acc[i][j][1] + b4.y;
      o.z = acc[i][j][2] + b4.z;
      o.w = acc[i][j][3] + b4.w;
      *(float4*)&out[(size_t)m * 768 + n] = o;
    }
  }
}

// ---------------- launch ----------------

extern "C" void kernel_launch(void* const* d_in, const int* in_sizes, int n_in,
                              void* d_out, int out_size, void* d_ws, size_t ws_size,
                              hipStream_t stream) {
  const float* x = (const float*)d_in[0];
  const float* bqkv = (const float*)d_in[2];
  const float* zeta = (const float*)d_in[3];
  const float* bproj = (const float*)d_in[5];
  const unsigned char* mask = (const unsigned char*)d_in[6];
  float* out = (float*)d_out;
  char* ws = (char*)d_ws;
  ushort_t* xb  = (ushort_t*)(ws);              // 16384x768 bf16
  ushort_t* WqT = (ushort_t*)(ws + 25165824);   // 2304x768 bf16
  ushort_t* WpT = (ushort_t*)(ws + 28704768);   // 768x768 bf16
  ushort_t* qb  = (ushort_t*)(ws + 29884416);   // (B,H,N,d) bf16
  ushort_t* kb  = (ushort_t*)(ws + 55050240);   // (B,H,N,d) bf16
  ushort_t* vtb = (ushort_t*)(ws + 80216064);   // (B,H,d,N) bf16
  ushort_t* ob  = xb;  // xb dead after k_qkv; reuse as attention output

  k_prep<<<dim3(8448), dim3(256), 0, stream>>>(x, xb, (const float*)d_in[1], WqT,
                                               (const float*)d_in[4], WpT);
  k_qkv<<<dim3(1152), dim3(256), 0, stream>>>(xb, WqT, bqkv, zeta, qb, kb, vtb);
  k_attn<<<dim3(1536), dim3(256), 0, stream>>>(qb, kb, vtb, mask, ob);
  k_proj<<<dim3(384), dim3(256), 0, stream>>>(ob, WpT, bproj, out);
}

// Round 5
// 290.238 us; speedup vs baseline: 1.6638x; 1.6638x over previous
//
#include <hip/hip_runtime.h>
#include <hip/hip_bf16.h>

typedef unsigned short ushort_t;
typedef __bf16 bf16_t;
typedef bf16_t bf16x8 __attribute__((ext_vector_type(8)));
typedef float floatx4 __attribute__((ext_vector_type(4)));
typedef ushort_t ushortx8 __attribute__((ext_vector_type(8)));

struct alignas(8) us4 { ushort_t x, y, z, w; };

__device__ __forceinline__ ushort_t f2bf(float f) {
  union { float f; unsigned int u; } v; v.f = f;
  unsigned int u = v.u;
  return (ushort_t)((u + 0x7fffu + ((u >> 16) & 1u)) >> 16);
}

__device__ __forceinline__ unsigned int pk_bf16(float a, float b) {
  __hip_bfloat162 h = __float22bfloat162_rn(float2{a, b});  // .x in low half
  union { __hip_bfloat162 h; unsigned int u; } v; v.h = h;
  return v.u;
}

__device__ __forceinline__ void async16(const void* g, void* l) {
  __builtin_amdgcn_global_load_lds(
      (const __attribute__((address_space(1))) unsigned int*)g,
      (__attribute__((address_space(3))) unsigned int*)l, 16, 0, 0);
}

#define LOG2E 1.44269504088896340736f

// ---------------- fused prep: cvt x -> bf16, transpose-cast W_qkv, W_proj ----

__global__ __launch_bounds__(256) void k_prep(const float* __restrict__ x,
                                              ushort_t* __restrict__ xb,
                                              const float* __restrict__ Wq,
                                              ushort_t* __restrict__ WqT,
                                              const float* __restrict__ Wp,
                                              ushort_t* __restrict__ WpT) {
  __shared__ float tile[32][33];
  const int bid = blockIdx.x, t = threadIdx.x;
  if (bid < 6144) {
    size_t i = ((size_t)bid * 256 + t) * 8;
    float4 a = *(const float4*)(x + i);
    float4 b = *(const float4*)(x + i + 4);
    ushortx8 o;
    o[0] = f2bf(a.x); o[1] = f2bf(a.y); o[2] = f2bf(a.z); o[3] = f2bf(a.w);
    o[4] = f2bf(b.x); o[5] = f2bf(b.y); o[6] = f2bf(b.z); o[7] = f2bf(b.w);
    *(ushortx8*)(xb + i) = o;
    return;
  }
  const float* in; ushort_t* out; int C, c0, r0;
  if (bid < 7872) {
    int b2 = bid - 6144;
    in = Wq; out = WqT; C = 2304;
    c0 = (b2 % 72) * 32; r0 = (b2 / 72) * 32;
  } else {
    int b3 = bid - 7872;
    in = Wp; out = WpT; C = 768;
    c0 = (b3 % 24) * 32; r0 = (b3 / 24) * 32;
  }
  const int tx = t & 31, ty = t >> 5;  // 32 x 8
#pragma unroll
  for (int i = 0; i < 32; i += 8)
    tile[ty + i][tx] = in[(size_t)(r0 + ty + i) * C + c0 + tx];
  __syncthreads();
#pragma unroll
  for (int i = 0; i < 32; i += 8)
    out[(size_t)(c0 + ty + i) * 768 + r0 + tx] = f2bf(tile[tx][ty + i]);
}

// ------ gemm_bt 3-stage pipelined mainloop (128x128 tile, K=768, BK=32) -----
// Known-good round-1 structure (measured 89.6us k_qkv, VGPR 72+64agpr=136
// fits the (256,3) cap of 170 -> no spill; 256-tile @occ3 spills: 212>170).
// 3 LDS buffers, prefetch 2 ahead, end-of-iter counted s_waitcnt vmcnt(4)
// + raw s_barrier. XOR-swizzle: 0 bank conflicts.
//
// SWAP=false: acc[i][j][r] -> m = m0+wr*64+i*16+qd*4+r, n = n0+wc*64+j*16+lr
// SWAP=true:  acc[i][j][r] -> m = m0+wr*64+i*16+lr,     n = n0+wc*64+j*16+qd*4+r

template <bool SWAP>
__device__ __forceinline__ void gemm_pipe3(const ushort_t* __restrict__ A,
                                           const ushort_t* __restrict__ Bt,
                                           int m0, int n0,
                                           ushort_t* sA, ushort_t* sB,
                                           floatx4 acc[4][4]) {
  const int t = threadIdx.x;
  const int lane = t & 63;
  const int lr = lane & 15, qd = lane >> 4;
  const int w = t >> 6;
  const int wr = w >> 1, wc = w & 1;
  const int swz = ((t & 3) ^ ((t >> 3) & 3)) * 8;
  const ushort_t* gA = A + (size_t)(m0 + (t >> 2)) * 768 + swz;
  const ushort_t* gB = Bt + (size_t)(n0 + (t >> 2)) * 768 + swz;
  char* lA = (char*)sA + t * 16;
  char* lB = (char*)sB + t * 16;
  const int rsz = (qd ^ ((lr >> 1) & 3)) * 16;
#define ISSUE(kk, buf)                                    \
  do {                                                    \
    const int k0_ = (kk) * 32, b_ = (buf) * 8192;         \
    async16(gA + k0_, lA + b_);                           \
    async16(gA + k0_ + 64 * 768, lA + b_ + 4096);         \
    async16(gB + k0_, lB + b_);                           \
    async16(gB + k0_ + 64 * 768, lB + b_ + 4096);         \
  } while (0)
  ISSUE(0, 0);
  ISSUE(1, 1);
  asm volatile("s_waitcnt vmcnt(4)" ::: "memory");  // k=0 landed
  asm volatile("s_barrier" ::: "memory");
#pragma unroll
  for (int k = 0; k < 24; ++k) {
    if (k + 2 < 24) ISSUE(k + 2, (k + 2) % 3);
    const char* cA = (const char*)sA + (k % 3) * 8192;
    const char* cB = (const char*)sB + (k % 3) * 8192;
    bf16x8 af[4], bfr[4];
#pragma unroll
    for (int i = 0; i < 4; ++i)
      af[i] = *(const bf16x8*)(cA + (wr * 64 + i * 16 + lr) * 64 + rsz);
#pragma unroll
    for (int j = 0; j < 4; ++j)
      bfr[j] = *(const bf16x8*)(cB + (wc * 64 + j * 16 + lr) * 64 + rsz);
#pragma unroll
    for (int i = 0; i < 4; ++i)
#pragma unroll
      for (int j = 0; j < 4; ++j) {
        if constexpr (SWAP)
          acc[i][j] = __builtin_amdgcn_mfma_f32_16x16x32_bf16(bfr[j], af[i], acc[i][j], 0, 0, 0);
        else
          acc[i][j] = __builtin_amdgcn_mfma_f32_16x16x32_bf16(af[i], bfr[j], acc[i][j], 0, 0, 0);
      }
    if (k < 22)
      asm volatile("s_waitcnt vmcnt(4)" ::: "memory");  // k+1 landed, k+2 in flight
    else if (k == 22)
      asm volatile("s_waitcnt vmcnt(0)" ::: "memory");  // only k=23's remain
    if (k < 23) asm volatile("s_barrier" ::: "memory");
  }
#undef ISSUE
}

// ---------------- QKV GEMM + bias + zeta + scale, scatter to q/k/vt ----------------
// XCD swizzle: per XCD, 16 consecutive blocks share an n-tile and cycle 16
// m-panels -> L2 working set ~3.3 MB < 4 MB.

__global__ __launch_bounds__(256, 3) void k_qkv(const ushort_t* __restrict__ xb,
                                                const ushort_t* __restrict__ WqT,
                                                const float* __restrict__ bqkv,
                                                const float* __restrict__ zeta,
                                                ushort_t* __restrict__ qb,
                                                ushort_t* __restrict__ kb,
                                                ushort_t* __restrict__ vtb) {
  __shared__ alignas(16) ushort_t sA[3 * 4096];
  __shared__ alignas(16) ushort_t sB[3 * 4096];
  floatx4 acc[4][4] = {};
  const int lin = blockIdx.x;
  const int xcd = lin & 7, idx = lin >> 3;           // idx in 0..287
  const int m0 = (xcd * 16 + (idx & 15)) * 128;      // 128 m-panels
  const int n0 = (idx >> 4) * 128;                   // 18 n-tiles
  const int tq = n0 / 768;  // 0=q 1=k 2=v (tile never straddles: 768 % 128 == 0)
  const int t = threadIdx.x, lane = t & 63, w = t >> 6;
  const int wr = w >> 1, wc = w & 1, lr = lane & 15, qd = lane >> 4;
  if (tq < 2) {
    gemm_pipe3<true>(xb, WqT, m0, n0, sA, sB, acc);
    ushort_t* dst = (tq == 0) ? qb : kb;
    const float sc = (tq == 0) ? 0.125f * LOG2E : 1.0f;
#pragma unroll
    for (int j = 0; j < 4; ++j) {
      int n = n0 + wc * 64 + j * 16 + qd * 4;   // + r along d
      int nc = n - tq * 768;
      int h = nc >> 6, dim = n & 63;
      float4 b4 = *(const float4*)&bqkv[n];
      float4 z4 = *(const float4*)&zeta[nc];
      float g0 = z4.x * sc, g1 = z4.y * sc, g2 = z4.z * sc, g3 = z4.w * sc;
#pragma unroll
      for (int i = 0; i < 4; ++i) {
        int m = m0 + wr * 64 + i * 16 + lr;
        int b = m >> 10, seq = m & 1023;
        us4 pk;
        pk.x = f2bf((acc[i][j][0] + b4.x) * g0);
        pk.y = f2bf((acc[i][j][1] + b4.y) * g1);
        pk.z = f2bf((acc[i][j][2] + b4.z) * g2);
        pk.w = f2bf((acc[i][j][3] + b4.w) * g3);
        *(us4*)&dst[(((size_t)b * 12 + h) * 1024 + seq) * 64 + dim] = pk;
      }
    }
  } else {
    gemm_pipe3<false>(xb, WqT, m0, n0, sA, sB, acc);
#pragma unroll
    for (int j = 0; j < 4; ++j) {
      int n = n0 + wc * 64 + j * 16 + lr;
      int nc = n - 2 * 768;
      int h = nc >> 6, dim = n & 63;
      float bias = bqkv[n];
      float zv = zeta[nc];
#pragma unroll
      for (int i = 0; i < 4; ++i) {
        int mbase = m0 + wr * 64 + i * 16 + qd * 4;
        int b = mbase >> 10, seq = mbase & 1023;
        us4 pk;
        pk.x = f2bf((acc[i][j][0] + bias) * zv);
        pk.y = f2bf((acc[i][j][1] + bias) * zv);
        pk.z = f2bf((acc[i][j][2] + bias) * zv);
        pk.w = f2bf((acc[i][j][3] + bias) * zv);
        *(us4*)&vtb[(((size_t)b * 12 + h) * 64 + dim) * 1024 + seq] = pk;
      }
    }
  }
}

// ---------------- flash attention v5.2: 64-key tiles, split K/V drains ------
// Per kt: issue K(kt+1) then V(kt+1) (order matters for counted vmcnt), QK,
// softmax, then vmcnt(4)+barrier (own V(kt) done; barrier makes all waves'
// V(kt) visible) before PV; end-of-iter vmcnt(2)+barrier (K(kt+1) landed,
// V(kt+1) still in flight -> gets QK+softmax of next iter to land).
// Per-wave outstanding ledger (2 K-loads + 2 V-loads per stage):
//   entry 2 (V kt) -> +4 issue = 6 -> vmcnt(4): V(kt) done -> PV
//   -> vmcnt(2): K(kt+1) done. Tail kt=15: vmcnt(0) before PV.
// Mask hoisted to LDS once. T5 setprio around MFMA clusters.
// LDS: 2x16KB stages + 16KB P + 4KB mask = 52KB; 3 blocks/CU.

__global__ __launch_bounds__(256, 3) void k_attn(const ushort_t* __restrict__ qg,
                                                 const ushort_t* __restrict__ kg,
                                                 const ushort_t* __restrict__ vg,
                                                 const unsigned char* __restrict__ mask,
                                                 ushort_t* __restrict__ ob) {
  __shared__ alignas(16) char smem[53248];
  // [0,16384): stage0 (K 8KB, V 8KB)  [16384,32768): stage1
  // [32768,49152): P (4KB/wave)       [49152,53248): maskadd[1024] f32
  float* maskadd = (float*)(smem + 49152);
  const int t = threadIdx.x, lane = t & 63, w = t >> 6;
  const int lr = lane & 15, qd = lane >> 4;
  const int lin = blockIdx.x;
  const int bh = (lin & 7) + 8 * (lin >> 6);
  const int qt = (lin >> 3) & 7;
  const int b = bh / 12, h = bh % 12;
  const int qrow0 = qt * 128 + w * 32;
  const ushort_t* qp = qg + (size_t)bh * 65536;
  const ushort_t* kp = kg + (size_t)bh * 65536;
  const ushort_t* vp = vg + (size_t)bh * 65536;
  const unsigned char* mp = mask + b * 1024;

  bf16x8 qf[2][2];
#pragma unroll
  for (int ns = 0; ns < 2; ++ns)
#pragma unroll
    for (int kk = 0; kk < 2; ++kk)
      qf[ns][kk] = *(const bf16x8*)(qp + (size_t)(qrow0 + ns * 16 + lr) * 64 + kk * 32 + qd * 8);

  floatx4 o[4][2] = {};
  float lst[2] = {0.f, 0.f};
  char* sPw = smem + 32768 + w * 4096;

  {  // mask -> LDS float table, once
    uchar4 mv = *(const uchar4*)(mp + t * 4);
    float4 f;
    f.x = mv.x ? -1e30f : 0.0f;
    f.y = mv.y ? -1e30f : 0.0f;
    f.z = mv.z ? -1e30f : 0.0f;
    f.w = mv.w ? -1e30f : 0.0f;
    *(float4*)&maskadd[t * 4] = f;
  }

  // K tile: 64 keys x 64 d (128B rows, XOR-swizzled 16B chunks)
#define STAGE_K(kt_, st_)                                                 \
  do {                                                                    \
    const ushort_t* kpt_ = kp + (kt_) * 4096;                             \
    _Pragma("unroll")                                                     \
    for (int it = 0; it < 2; ++it) {                                      \
      int p = it * 256 + t;                                               \
      int r = p >> 3, cs = (p & 7) ^ (r & 7);                             \
      async16(kpt_ + r * 64 + cs * 8, smem + (st_) * 16384 + p * 16);     \
    }                                                                     \
  } while (0)
  // V tile: 64 d x 64 seq (128B rows, XOR-swizzled 16B chunks)
#define STAGE_V(kt_, st_)                                                 \
  do {                                                                    \
    const ushort_t* vpt_ = vp + (kt_) * 64;                               \
    _Pragma("unroll")                                                     \
    for (int it = 0; it < 2; ++it) {                                      \
      int p = it * 256 + t;                                               \
      int r = p >> 3, cs = (p & 7) ^ (r & 7);                             \
      async16(vpt_ + (size_t)r * 1024 + cs * 8,                           \
              smem + (st_) * 16384 + 8192 + p * 16);                      \
    }                                                                     \
  } while (0)

  STAGE_K(0, 0);
  STAGE_V(0, 0);
  __syncthreads();  // drains prologue DMA + mask writes

#pragma unroll 2
  for (int kt = 0; kt < 16; ++kt) {
    const int st = kt & 1;
    if (kt + 1 < 16) {
      STAGE_K(kt + 1, st ^ 1);   // issued first -> oldest
      STAGE_V(kt + 1, st ^ 1);
    }
    const char* sK = smem + st * 16384;
    const char* sV = smem + st * 16384 + 8192;

    floatx4 s[4][2] = {};
    __builtin_amdgcn_s_setprio(1);
#pragma unroll
    for (int kk = 0; kk < 2; ++kk) {
#pragma unroll
      for (int ms = 0; ms < 4; ++ms) {
        bf16x8 ak = *(const bf16x8*)(sK + (ms * 16 + lr) * 128 +
                                     ((kk * 4 + qd) ^ (lr & 7)) * 16);
#pragma unroll
        for (int ns = 0; ns < 2; ++ns)
          s[ms][ns] = __builtin_amdgcn_mfma_f32_16x16x32_bf16(ak, qf[ns][kk], s[ms][ns], 0, 0, 0);
      }
    }
    __builtin_amdgcn_s_setprio(0);

#pragma unroll
    for (int ms = 0; ms < 4; ++ms) {
      float4 mk = *(const float4*)&maskadd[kt * 64 + ms * 16 + qd * 4];
#pragma unroll
      for (int ns = 0; ns < 2; ++ns) {
        float p0 = __builtin_amdgcn_exp2f(s[ms][ns][0] + mk.x);
        float p1 = __builtin_amdgcn_exp2f(s[ms][ns][1] + mk.y);
        float p2 = __builtin_amdgcn_exp2f(s[ms][ns][2] + mk.z);
        float p3 = __builtin_amdgcn_exp2f(s[ms][ns][3] + mk.w);
        lst[ns] += (p0 + p1) + (p2 + p3);
        uint2 pk;
        pk.x = pk_bf16(p0, p1);
        pk.y = pk_bf16(p2, p3);
        *(uint2*)(sPw + (ns * 16 + lr) * 128 +
                  ((ms * 2 + (qd >> 1)) ^ (lr & 7)) * 16 + (qd & 1) * 8) = pk;
      }
    }
    asm volatile("s_waitcnt lgkmcnt(0)" ::: "memory");
    __builtin_amdgcn_sched_barrier(0);

    // V(kt) drain: own loads via counted vmcnt, cross-wave via barrier.
    if (kt + 1 < 16)
      asm volatile("s_waitcnt vmcnt(4)" ::: "memory");  // oldest (V kt) done
    else
      asm volatile("s_waitcnt vmcnt(0)" ::: "memory");  // tail: nothing newer
    asm volatile("s_barrier" ::: "memory");

    __builtin_amdgcn_s_setprio(1);
#pragma unroll
    for (int kk = 0; kk < 2; ++kk) {
      bf16x8 pb[2];
#pragma unroll
      for (int ns = 0; ns < 2; ++ns)
        pb[ns] = *(const bf16x8*)(sPw + (ns * 16 + lr) * 128 +
                                  ((kk * 4 + qd) ^ (lr & 7)) * 16);
#pragma unroll
      for (int ds = 0; ds < 4; ++ds) {
        bf16x8 av = *(const bf16x8*)(sV + (ds * 16 + lr) * 128 +
                                     ((kk * 4 + qd) ^ (lr & 7)) * 16);
#pragma unroll
        for (int ns = 0; ns < 2; ++ns)
          o[ds][ns] = __builtin_amdgcn_mfma_f32_16x16x32_bf16(av, pb[ns], o[ds][ns], 0, 0, 0);
      }
    }
    __builtin_amdgcn_s_setprio(0);

    if (kt + 1 < 16) {
      asm volatile("s_waitcnt vmcnt(2)" ::: "memory");  // K(kt+1) landed
      asm volatile("s_barrier" ::: "memory");           // st safe to overwrite
    }
  }
#undef STAGE_K
#undef STAGE_V

#pragma unroll
  for (int ns = 0; ns < 2; ++ns) {
    lst[ns] += __shfl_xor(lst[ns], 16);
    lst[ns] += __shfl_xor(lst[ns], 32);
  }
#pragma unroll
  for (int ns = 0; ns < 2; ++ns) {
    float rl = 1.0f / lst[ns];
    size_t row = (size_t)(b * 1024 + qrow0 + ns * 16 + lr) * 768 + h * 64;
#pragma unroll
    for (int ds = 0; ds < 4; ++ds) {
      uint2 ov;
      ov.x = pk_bf16(o[ds][ns][0] * rl, o[ds][ns][1] * rl);
      ov.y = pk_bf16(o[ds][ns][2] * rl, o[ds][ns][3] * rl);
      *(uint2*)&ob[row + ds * 16 + qd * 4] = ov;
    }
  }
}

// ---------------- output projection (SWAP=true -> float4 stores) ------------

__global__ __launch_bounds__(256, 3) void k_proj(const ushort_t* __restrict__ ob,
                                                 const ushort_t* __restrict__ WpT,
                                                 const float* __restrict__ bproj,
                                                 float* __restrict__ out) {
  __shared__ alignas(16) ushort_t sA[3 * 4096];
  __shared__ alignas(16) ushort_t sB[3 * 4096];
  floatx4 acc[4][4] = {};
  const int lin = blockIdx.x;
  const int xcd = lin & 7, idx = lin >> 3;           // idx in 0..95
  const int m0 = (xcd * 16 + (idx & 15)) * 128;
  const int n0 = (idx >> 4) * 128;                   // 6 n-tiles
  gemm_pipe3<true>(ob, WpT, m0, n0, sA, sB, acc);
  const int t = threadIdx.x, lane = t & 63, w = t >> 6;
  const int wr = w >> 1, wc = w & 1, lr = lane & 15, qd = lane >> 4;
#pragma unroll
  for (int j = 0; j < 4; ++j) {
    int n = n0 + wc * 64 + j * 16 + qd * 4;
    float4 b4 = *(const float4*)&bproj[n];
#pragma unroll
    for (int i = 0; i < 4; ++i) {
      int m = m0 + wr * 64 + i * 16 + lr;
      float4 o;
      o.x = acc[i][j][0] + b4.x;
      o.y = acc[i][j][1] + b4.y;
      o.z = acc[i][j][2] + b4.z;
      o.w = acc[i][j][3] + b4.w;
      *(float4*)&out[(size_t)m * 768 + n] = o;
    }
  }
}

// ---------------- launch ----------------

extern "C" void kernel_launch(void* const* d_in, const int* in_sizes, int n_in,
                              void* d_out, int out_size, void* d_ws, size_t ws_size,
                              hipStream_t stream) {
  const float* x = (const float*)d_in[0];
  const float* bqkv = (const float*)d_in[2];
  const float* zeta = (const float*)d_in[3];
  const float* bproj = (const float*)d_in[5];
  const unsigned char* mask = (const unsigned char*)d_in[6];
  float* out = (float*)d_out;
  char* ws = (char*)d_ws;
  ushort_t* xb  = (ushort_t*)(ws);              // 16384x768 bf16
  ushort_t* WqT = (ushort_t*)(ws + 25165824);   // 2304x768 bf16
  ushort_t* WpT = (ushort_t*)(ws + 28704768);   // 768x768 bf16
  ushort_t* qb  = (ushort_t*)(ws + 29884416);   // (B,H,N,d) bf16
  ushort_t* kb  = (ushort_t*)(ws + 55050240);   // (B,H,N,d) bf16
  ushort_t* vtb = (ushort_t*)(ws + 80216064);   // (B,H,d,N) bf16
  ushort_t* ob  = xb;  // xb dead after k_qkv; reuse as attention output

  k_prep<<<dim3(8448), dim3(256), 0, stream>>>(x, xb, (const float*)d_in[1], WqT,
                                               (const float*)d_in[4], WpT);
  k_qkv<<<dim3(2304), dim3(256), 0, stream>>>(xb, WqT, bqkv, zeta, qb, kb, vtb);
  k_attn<<<dim3(1536), dim3(256), 0, stream>>>(qb, kb, vtb, mask, ob);
  k_proj<<<dim3(768), dim3(256), 0, stream>>>(ob, WpT, bproj, out);
}